// Round 10
// baseline (292.514 us; speedup 1.0000x reference)
//
#include <hip/hip_runtime.h>
#include <hip/hip_bf16.h>
#include <cstdint>
#include <cstddef>

#define PI_F 3.14159265358979323846f
#define TWO_PI_F 6.28318530717958647692f

typedef __bf16 bf16x8 __attribute__((ext_vector_type(8)));
typedef __bf16 bf16x4 __attribute__((ext_vector_type(4)));
typedef float  f32x4  __attribute__((ext_vector_type(4)));

__device__ __forceinline__ __bf16 to_bf16(float f) { return (__bf16)f; }

// global -> LDS async copy, 16B per lane; LDS dest = wave-uniform base + lane*16
#define GLD_LDS16(gsrc, ldst)                                            \
  __builtin_amdgcn_global_load_lds(                                      \
      (const __attribute__((address_space(1))) void*)(gsrc),             \
      (__attribute__((address_space(3))) void*)(ldst), 16, 0, 0)

// ---------------------------------------------------------------------------
// Kernel P: per-(layer,pair) beamsplitter params -> ws table.
// ---------------------------------------------------------------------------
__global__ __launch_bounds__(256) void olk_params(
    const float* __restrict__ theta, const float* __restrict__ phi,
    float4* __restrict__ t4, float2* __restrict__ t2) {
  int idx = blockIdx.x * 256 + threadIdx.x;  // 256*128 = 32768 total
  float t = fmodf(theta[idx], PI_F);
  float p = phi[idx];
  if (t > 0.5f * PI_F) { t = PI_F - t; p += PI_F; }
  p = fmodf(p, TWO_PI_F);
  float c  = cosf(t), s  = sinf(t);
  float cp = cosf(p), sp = sinf(p);
  t4[idx] = make_float4(cp * c, sp * c, cp * s, sp * s);
  t2[idx] = make_float2(c, s);
}

// ---------------------------------------------------------------------------
// Build kernel (unchanged, proven): V = e_r^T, V <- V*T_l, l=255..0.
// ---------------------------------------------------------------------------
struct P8 {
  float4 qa[8];
  float4 qb[8];
  float4 cc[8];
};

__device__ __forceinline__ void loadP8(P8& P, int lb, int lane,
    const float4* __restrict__ t4, const float2* __restrict__ t2) {
#pragma unroll
  for (int k = 0; k < 8; ++k) {
    int idx = (lb + k) * 128 + 2 * lane;
    P.qa[k] = t4[idx];
    P.qb[k] = t4[idx + 1];
    P.cc[k] = *(const float4*)&t2[idx];
  }
}

__device__ __forceinline__ void layer_step(bool odd, int lane,
    float4 qa, float4 qb, float4 cc,
    float& vre0, float& vim0, float& vre1, float& vim1,
    float& vre2, float& vim2, float& vre3, float& vim3) {
  if (!odd) {
    float nr0 = qa.x * vre0 - qa.y * vim0 + qa.z * vre1 - qa.w * vim1;
    float ni0 = qa.x * vim0 + qa.y * vre0 + qa.z * vim1 + qa.w * vre1;
    float nr1 = cc.x * vre1 - cc.y * vre0;
    float ni1 = cc.x * vim1 - cc.y * vim0;
    float nr2 = qb.x * vre2 - qb.y * vim2 + qb.z * vre3 - qb.w * vim3;
    float ni2 = qb.x * vim2 + qb.y * vre2 + qb.z * vim3 + qb.w * vre3;
    float nr3 = cc.z * vre3 - cc.w * vre2;
    float ni3 = cc.z * vim3 - cc.w * vim2;
    vre0 = nr0; vim0 = ni0; vre1 = nr1; vim1 = ni1;
    vre2 = nr2; vim2 = ni2; vre3 = nr3; vim3 = ni3;
  } else {
    int nxt = (lane + 1) & 63, prv = (lane + 63) & 63;
    float xre = __shfl(vre0, nxt, 64);
    float xim = __shfl(vim0, nxt, 64);
    float pre = __shfl(vre3, prv, 64);
    float pim = __shfl(vim3, prv, 64);
    float cp  = __shfl(cc.z, prv, 64);
    float sp  = __shfl(cc.w, prv, 64);
    float nr1 = qa.x * vre1 - qa.y * vim1 + qa.z * vre2 - qa.w * vim2;
    float ni1 = qa.x * vim1 + qa.y * vre1 + qa.z * vim2 + qa.w * vre2;
    float nr2 = cc.x * vre2 - cc.y * vre1;
    float ni2 = cc.x * vim2 - cc.y * vim1;
    float nr3 = qb.x * vre3 - qb.y * vim3 + qb.z * xre - qb.w * xim;
    float ni3 = qb.x * vim3 + qb.y * vre3 + qb.z * xim + qb.w * xre;
    float nr0 = cp * vre0 - sp * pre;
    float ni0 = cp * vim0 - sp * pim;
    vre0 = nr0; vim0 = ni0; vre1 = nr1; vim1 = ni1;
    vre2 = nr2; vim2 = ni2; vre3 = nr3; vim3 = ni3;
  }
}

__global__ __launch_bounds__(256) void olk_build(
    const float* __restrict__ outph,
    const float4* __restrict__ t4, const float2* __restrict__ t2,
    __bf16* __restrict__ Tb2) {
  int lane = threadIdx.x & 63;
  int r = blockIdx.x * 4 + (threadIdx.x >> 6);
  int c0 = lane * 4;
  float vre0 = (c0 + 0 == r) ? 1.f : 0.f, vim0 = 0.f;
  float vre1 = (c0 + 1 == r) ? 1.f : 0.f, vim1 = 0.f;
  float vre2 = (c0 + 2 == r) ? 1.f : 0.f, vim2 = 0.f;
  float vre3 = (c0 + 3 == r) ? 1.f : 0.f, vim3 = 0.f;

  P8 A, B;
  loadP8(A, 31 * 8, lane, t4, t2);
  for (int it = 0; it < 16; ++it) {
    int bA = 31 - 2 * it;
    int bB = bA - 1;
    loadP8(B, bB * 8, lane, t4, t2);
#pragma unroll
    for (int k = 7; k >= 0; --k)
      layer_step((k & 1) != 0, lane, A.qa[k], A.qb[k], A.cc[k],
                 vre0, vim0, vre1, vim1, vre2, vim2, vre3, vim3);
    if (it < 15)
      loadP8(A, (bB - 1) * 8, lane, t4, t2);
#pragma unroll
    for (int k = 7; k >= 0; --k)
      layer_step((k & 1) != 0, lane, B.qa[k], B.qb[k], B.cc[k],
                 vre0, vim0, vre1, vim1, vre2, vim2, vre3, vim3);
  }

  float oph = outph[r];
  float co = cosf(oph), so = sinf(oph);
  bf16x4 o;
  o[0] = to_bf16(co * vre0 - so * vim0);
  o[1] = to_bf16(co * vre1 - so * vim1);
  o[2] = to_bf16(co * vre2 - so * vim2);
  o[3] = to_bf16(co * vre3 - so * vim3);

  int ks = lane >> 3, sub = lane & 7;
  int pos = ks * 32 + (sub & 3) * 8 + (sub >> 2) * 4;
  *(bf16x4*)(Tb2 + r * 256 + pos) = o;
}

// ---------------------------------------------------------------------------
// PROBE A: R4-pattern reads (16 x dwordx4 bursts per wave-tile), asm-consumed.
// 1024 blocks x 4 waves, 2 tiles/wave, 4 sweeps of x. VGPR ~80, 16 waves/CU.
// ---------------------------------------------------------------------------
__global__ __launch_bounds__(256, 4) void probe_burst(const float* __restrict__ x) {
  int tid = threadIdx.x, lane = tid & 63, w = tid >> 6;
  int g = blockIdx.x * 4 + w;
  int l15 = lane & 15, lg = lane >> 4;
#pragma unroll 1
  for (int rep = 0; rep < 4; ++rep) {
    unsigned zo = 0;
    asm volatile("" : "+v"(zo));            // defeat cross-rep CSE
#pragma unroll 1
    for (int t = 0; t < 2; ++t) {
      const float* xr = x + ((size_t)((2 * g + t) * 16 + l15) << 8) + 4 * lg + zo;
      f32x4 L[16];
      __builtin_amdgcn_sched_barrier(0);
#pragma unroll
      for (int ks = 0; ks < 8; ++ks) {
        L[2 * ks]     = __builtin_nontemporal_load((const f32x4*)(xr + ks * 32));
        L[2 * ks + 1] = __builtin_nontemporal_load((const f32x4*)(xr + ks * 32 + 16));
      }
      __builtin_amdgcn_sched_barrier(0);
#pragma unroll
      for (int i = 0; i < 16; ++i) asm volatile("" :: "v"(L[i]));  // consume
    }
  }
}

// ---------------------------------------------------------------------------
// PROBE B: m13/m146-style streaming: grid-stride, unroll-8, 32 waves/CU.
// 2048 blocks x 256 thr; 8.39M float4s of x per sweep; 4 sweeps.
// ---------------------------------------------------------------------------
__global__ __launch_bounds__(256) void probe_stream(const float* __restrict__ x) {
  const f32x4* xv = (const f32x4*)x;
  const size_t NT = (size_t)2048 * 256;        // 524288 threads
  size_t base = (size_t)blockIdx.x * 256 + threadIdx.x;
#pragma unroll 1
  for (int rep = 0; rep < 4; ++rep) {
    unsigned zo = 0;
    asm volatile("" : "+v"(zo));
#pragma unroll 1
    for (size_t i = base + zo; i < 8388608; i += NT * 8) {
      f32x4 v0 = __builtin_nontemporal_load(&xv[i]);
      f32x4 v1 = __builtin_nontemporal_load(&xv[i + NT]);
      f32x4 v2 = __builtin_nontemporal_load(&xv[i + NT * 2]);
      f32x4 v3 = __builtin_nontemporal_load(&xv[i + NT * 3]);
      f32x4 v4 = __builtin_nontemporal_load(&xv[i + NT * 4]);
      f32x4 v5 = __builtin_nontemporal_load(&xv[i + NT * 5]);
      f32x4 v6 = __builtin_nontemporal_load(&xv[i + NT * 6]);
      f32x4 v7 = __builtin_nontemporal_load(&xv[i + NT * 7]);
      asm volatile("" :: "v"(v0), "v"(v1), "v"(v2), "v"(v3));
      asm volatile("" :: "v"(v4), "v"(v5), "v"(v6), "v"(v7));
    }
  }
}

// ---------------------------------------------------------------------------
// PROBE C: global_load_lds DMA ring (R6 path), vmcnt(16)-paced, no compute.
// 1024 blocks x 4 waves, per-wave private 2x16KB slots (64KB/block,
// 2 blocks/CU -> ~192KB/CU in flight), 2 tiles/wave, 4 sweeps.
// ---------------------------------------------------------------------------
__global__ __launch_bounds__(256, 2) void probe_dma(const float* __restrict__ x,
                                                    float* __restrict__ sink) {
  __shared__ float4 sb[4][2][1024];   // [wave][slot][chunk] = 64KB
  int tid = threadIdx.x, lane = tid & 63, w = tid >> 6;
  int g = blockIdx.x * 4 + w;

#pragma unroll 1
  for (int rep = 0; rep < 4; ++rep) {
#pragma unroll 1
    for (int t = 0; t < 2; ++t) {
      const float* base = x + ((size_t)(2 * g + t) << 12);
#pragma unroll
      for (int i = 0; i < 16; ++i)
        GLD_LDS16(base + i * 256 + (lane << 2), &sb[w][t][i * 64]);
      // keep 16 newest outstanding; wait the previous batch
      asm volatile("s_waitcnt vmcnt(16)" ::: "memory");
    }
  }
  asm volatile("s_waitcnt vmcnt(0)" ::: "memory");
  if (blockIdx.x == 0xFFFFFF)                   // never true: keep LDS live
    sink[tid] = ((float*)sb)[tid];
}

// ---------------------------------------------------------------------------
// Matmul (R9's passing version, unchanged) — launched LAST, writes out.
// ---------------------------------------------------------------------------
__global__ __launch_bounds__(256, 4) void olk_mm(
    const float* __restrict__ x, const __bf16* __restrict__ Tb2,
    float* __restrict__ out) {
  __shared__ __bf16 Bl[32 * 512];
  int tid = threadIdx.x, lane = tid & 63, w = tid >> 6;
  int l15 = lane & 15, lg = lane >> 4;

  int mt0 = (blockIdx.x * 4 + w) * 2;

  f32x4 L[16];
  bf16x8 a[8];
  f32x4 acc[4];

#define ISSUE(t)                                                          \
  do {                                                                    \
    const float* xr_ = x + ((size_t)((t) * 16 + l15) << 8) + 4 * lg;      \
    __builtin_amdgcn_sched_barrier(0);                                    \
    _Pragma("unroll")                                                     \
    for (int ks = 0; ks < 8; ++ks) {                                      \
      L[2 * ks]     = __builtin_nontemporal_load((const f32x4*)(xr_ + ks * 32));      \
      L[2 * ks + 1] = __builtin_nontemporal_load((const f32x4*)(xr_ + ks * 32 + 16)); \
    }                                                                     \
    __builtin_amdgcn_sched_barrier(0);                                    \
  } while (0)

#define CVT()                                                             \
  do {                                                                    \
    _Pragma("unroll")                                                     \
    for (int ks = 0; ks < 8; ++ks) {                                      \
      f32x4 lo_ = L[2 * ks], hi_ = L[2 * ks + 1];                         \
      bf16x8 v_;                                                          \
      v_[0] = to_bf16(lo_.x); v_[1] = to_bf16(lo_.y);                     \
      v_[2] = to_bf16(lo_.z); v_[3] = to_bf16(lo_.w);                     \
      v_[4] = to_bf16(hi_.x); v_[5] = to_bf16(hi_.y);                     \
      v_[6] = to_bf16(hi_.z); v_[7] = to_bf16(hi_.w);                     \
      a[ks] = v_;                                                         \
    }                                                                     \
  } while (0)

#define MFMA(bb)                                                          \
  do {                                                                    \
    _Pragma("unroll")                                                     \
    for (int nt = 0; nt < 4; ++nt) acc[nt] = (f32x4){0.f, 0.f, 0.f, 0.f}; \
    _Pragma("unroll")                                                     \
    for (int ks = 0; ks < 8; ++ks)                                        \
      _Pragma("unroll")                                                   \
      for (int nt = 0; nt < 4; ++nt) {                                    \
        bf16x8 bv_ = *(const bf16x8*)&Bl[(bb) + (ks * 4 + nt) * 512 + lane * 8]; \
        acc[nt] = __builtin_amdgcn_mfma_f32_16x16x32_bf16(a[ks], bv_, acc[nt], 0, 0, 0); \
      }                                                                   \
  } while (0)

#define STORE(t)                                                          \
  do {                                                                    \
    float* ob_ = out + ((size_t)(t) * 16) * 64 + l15;                     \
    _Pragma("unroll")                                                     \
    for (int r = 0; r < 4; ++r)                                           \
      _Pragma("unroll")                                                   \
      for (int nt = 0; nt < 4; ++nt)                                      \
        __builtin_nontemporal_store(acc[nt][r], &ob_[(4 * lg + r) * 64 + nt * 16]); \
  } while (0)

  ISSUE(mt0);

#pragma unroll
  for (int j = 0; j < 8; ++j) {
    int idx = w * 8 + j;
    int ks = idx >> 2, nt = idx & 3;
    const __bf16* src = Tb2 + (nt * 16 + l15) * 256 + ks * 32 + lg * 8;
    GLD_LDS16(src, &Bl[idx * 512]);
  }
  __syncthreads();

  unsigned bb = 0;
  asm volatile("" : "+v"(bb));

  CVT();
  ISSUE(mt0 + 1);
  MFMA(bb);
  STORE(mt0);
  CVT();
  MFMA(bb);
  STORE(mt0 + 1);

#undef ISSUE
#undef CVT
#undef MFMA
#undef STORE
}

// ---------------------------------------------------------------------------
extern "C" void kernel_launch(void* const* d_in, const int* in_sizes, int n_in,
                              void* d_out, int out_size, void* d_ws, size_t ws_size,
                              hipStream_t stream) {
  const float* x     = (const float*)d_in[0];
  const float* theta = (const float*)d_in[1];
  const float* phi   = (const float*)d_in[2];
  const float* outph = (const float*)d_in[3];
  float* out = (float*)d_out;

  char* ws = (char*)d_ws;
  float4* t4  = (float4*)ws;                      // 512 KB
  float2* t2  = (float2*)(ws + 512 * 1024);       // 256 KB
  __bf16* Tb2 = (__bf16*)(ws + 768 * 1024);       // 32 KB frag-ordered T
  float* sink = (float*)(ws + 1024 * 1024);       // probe C dummy sink

  olk_params<<<128, 256, 0, stream>>>(theta, phi, t4, t2);
  olk_build<<<16, 256, 0, stream>>>(outph, t4, t2, Tb2);
  // --- instrumentation probes (read-only on x; ~90-220us each, top-5 visible)
  probe_burst<<<1024, 256, 0, stream>>>(x);
  probe_stream<<<2048, 256, 0, stream>>>(x);
  probe_dma<<<1024, 256, 0, stream>>>(x, sink);
  // --- real computation last (writes out)
  olk_mm<<<1024, 256, 0, stream>>>(x, Tb2, out);
}

// Round 11
// 120.863 us; speedup vs baseline: 2.4202x; 2.4202x over previous
//
#include <hip/hip_runtime.h>
#include <hip/hip_bf16.h>
#include <cstdint>
#include <cstddef>

#define PI_F 3.14159265358979323846f
#define TWO_PI_F 6.28318530717958647692f

typedef __bf16 bf16x8 __attribute__((ext_vector_type(8)));
typedef __bf16 bf16x4 __attribute__((ext_vector_type(4)));
typedef float  f32x4  __attribute__((ext_vector_type(4)));

__device__ __forceinline__ __bf16 to_bf16(float f) { return (__bf16)f; }

// global -> LDS async copy, 16B per lane; LDS dest = wave-uniform base + lane*16
#define GLD_LDS16(gsrc, ldst)                                            \
  __builtin_amdgcn_global_load_lds(                                      \
      (const __attribute__((address_space(1))) void*)(gsrc),             \
      (__attribute__((address_space(3))) void*)(ldst), 16, 0, 0)

// ---------------------------------------------------------------------------
// Kernel P: per-(layer,pair) beamsplitter params -> ws table.
// ---------------------------------------------------------------------------
__global__ __launch_bounds__(256) void olk_params(
    const float* __restrict__ theta, const float* __restrict__ phi,
    float4* __restrict__ t4, float2* __restrict__ t2) {
  int idx = blockIdx.x * 256 + threadIdx.x;  // 256*128 = 32768 total
  float t = fmodf(theta[idx], PI_F);
  float p = phi[idx];
  if (t > 0.5f * PI_F) { t = PI_F - t; p += PI_F; }
  p = fmodf(p, TWO_PI_F);
  float c  = cosf(t), s  = sinf(t);
  float cp = cosf(p), sp = sinf(p);
  t4[idx] = make_float4(cp * c, sp * c, cp * s, sp * s);
  t2[idx] = make_float2(c, s);
}

// ---------------------------------------------------------------------------
// Build kernel (unchanged, proven): V = e_r^T, V <- V*T_l, l=255..0.
// ---------------------------------------------------------------------------
struct P8 {
  float4 qa[8];
  float4 qb[8];
  float4 cc[8];
};

__device__ __forceinline__ void loadP8(P8& P, int lb, int lane,
    const float4* __restrict__ t4, const float2* __restrict__ t2) {
#pragma unroll
  for (int k = 0; k < 8; ++k) {
    int idx = (lb + k) * 128 + 2 * lane;
    P.qa[k] = t4[idx];
    P.qb[k] = t4[idx + 1];
    P.cc[k] = *(const float4*)&t2[idx];
  }
}

__device__ __forceinline__ void layer_step(bool odd, int lane,
    float4 qa, float4 qb, float4 cc,
    float& vre0, float& vim0, float& vre1, float& vim1,
    float& vre2, float& vim2, float& vre3, float& vim3) {
  if (!odd) {
    float nr0 = qa.x * vre0 - qa.y * vim0 + qa.z * vre1 - qa.w * vim1;
    float ni0 = qa.x * vim0 + qa.y * vre0 + qa.z * vim1 + qa.w * vre1;
    float nr1 = cc.x * vre1 - cc.y * vre0;
    float ni1 = cc.x * vim1 - cc.y * vim0;
    float nr2 = qb.x * vre2 - qb.y * vim2 + qb.z * vre3 - qb.w * vim3;
    float ni2 = qb.x * vim2 + qb.y * vre2 + qb.z * vim3 + qb.w * vre3;
    float nr3 = cc.z * vre3 - cc.w * vre2;
    float ni3 = cc.z * vim3 - cc.w * vim2;
    vre0 = nr0; vim0 = ni0; vre1 = nr1; vim1 = ni1;
    vre2 = nr2; vim2 = ni2; vre3 = nr3; vim3 = ni3;
  } else {
    int nxt = (lane + 1) & 63, prv = (lane + 63) & 63;
    float xre = __shfl(vre0, nxt, 64);
    float xim = __shfl(vim0, nxt, 64);
    float pre = __shfl(vre3, prv, 64);
    float pim = __shfl(vim3, prv, 64);
    float cp  = __shfl(cc.z, prv, 64);
    float sp  = __shfl(cc.w, prv, 64);
    float nr1 = qa.x * vre1 - qa.y * vim1 + qa.z * vre2 - qa.w * vim2;
    float ni1 = qa.x * vim1 + qa.y * vre1 + qa.z * vim2 + qa.w * vre2;
    float nr2 = cc.x * vre2 - cc.y * vre1;
    float ni2 = cc.x * vim2 - cc.y * vim1;
    float nr3 = qb.x * vre3 - qb.y * vim3 + qb.z * xre - qb.w * xim;
    float ni3 = qb.x * vim3 + qb.y * vre3 + qb.z * xim + qb.w * xre;
    float nr0 = cp * vre0 - sp * pre;
    float ni0 = cp * vim0 - sp * pim;
    vre0 = nr0; vim0 = ni0; vre1 = nr1; vim1 = ni1;
    vre2 = nr2; vim2 = ni2; vre3 = nr3; vim3 = ni3;
  }
}

__global__ __launch_bounds__(256) void olk_build(
    const float* __restrict__ outph,
    const float4* __restrict__ t4, const float2* __restrict__ t2,
    __bf16* __restrict__ Tb2) {
  int lane = threadIdx.x & 63;
  int r = blockIdx.x * 4 + (threadIdx.x >> 6);
  int c0 = lane * 4;
  float vre0 = (c0 + 0 == r) ? 1.f : 0.f, vim0 = 0.f;
  float vre1 = (c0 + 1 == r) ? 1.f : 0.f, vim1 = 0.f;
  float vre2 = (c0 + 2 == r) ? 1.f : 0.f, vim2 = 0.f;
  float vre3 = (c0 + 3 == r) ? 1.f : 0.f, vim3 = 0.f;

  P8 A, B;
  loadP8(A, 31 * 8, lane, t4, t2);
  for (int it = 0; it < 16; ++it) {
    int bA = 31 - 2 * it;
    int bB = bA - 1;
    loadP8(B, bB * 8, lane, t4, t2);
#pragma unroll
    for (int k = 7; k >= 0; --k)
      layer_step((k & 1) != 0, lane, A.qa[k], A.qb[k], A.cc[k],
                 vre0, vim0, vre1, vim1, vre2, vim2, vre3, vim3);
    if (it < 15)
      loadP8(A, (bB - 1) * 8, lane, t4, t2);
#pragma unroll
    for (int k = 7; k >= 0; --k)
      layer_step((k & 1) != 0, lane, B.qa[k], B.qb[k], B.cc[k],
                 vre0, vim0, vre1, vim1, vre2, vim2, vre3, vim3);
  }

  float oph = outph[r];
  float co = cosf(oph), so = sinf(oph);
  bf16x4 o;
  o[0] = to_bf16(co * vre0 - so * vim0);
  o[1] = to_bf16(co * vre1 - so * vim1);
  o[2] = to_bf16(co * vre2 - so * vim2);
  o[3] = to_bf16(co * vre3 - so * vim3);

  int ks = lane >> 3, sub = lane & 7;
  int pos = ks * 32 + (sub & 3) * 8 + (sub >> 2) * 4;
  *(bf16x4*)(Tb2 + r * 256 + pos) = o;
}

// ---------------------------------------------------------------------------
// Matmul, DIAGNOSTIC x2: the R4/R9 body executed twice inside one dispatch
// (opaque rep offset; pass 2 rewrites identical values). dur ~= 2M > fills
// -> olk_mm finally lands in the top-5 WITH counters (VGPR_Count, Occupancy,
// FETCH/WRITE, VALUBusy). Structure otherwise identical to R9's passing mm.
// ---------------------------------------------------------------------------
__global__ __launch_bounds__(256, 4) void olk_mm(
    const float* __restrict__ x, const __bf16* __restrict__ Tb2,
    float* __restrict__ out) {
  __shared__ __bf16 Bl[32 * 512];
  int tid = threadIdx.x, lane = tid & 63, w = tid >> 6;
  int l15 = lane & 15, lg = lane >> 4;

  int mt0 = (blockIdx.x * 4 + w) * 2;

  f32x4 L[16];
  bf16x8 a[8];
  f32x4 acc[4];

#define ISSUE(t, zo)                                                      \
  do {                                                                    \
    const float* xr_ = x + ((size_t)((t) * 16 + l15) << 8) + 4 * lg + (zo); \
    __builtin_amdgcn_sched_barrier(0);                                    \
    _Pragma("unroll")                                                     \
    for (int ks = 0; ks < 8; ++ks) {                                      \
      L[2 * ks]     = __builtin_nontemporal_load((const f32x4*)(xr_ + ks * 32));      \
      L[2 * ks + 1] = __builtin_nontemporal_load((const f32x4*)(xr_ + ks * 32 + 16)); \
    }                                                                     \
    __builtin_amdgcn_sched_barrier(0);                                    \
  } while (0)

#define CVT()                                                             \
  do {                                                                    \
    _Pragma("unroll")                                                     \
    for (int ks = 0; ks < 8; ++ks) {                                      \
      f32x4 lo_ = L[2 * ks], hi_ = L[2 * ks + 1];                         \
      bf16x8 v_;                                                          \
      v_[0] = to_bf16(lo_.x); v_[1] = to_bf16(lo_.y);                     \
      v_[2] = to_bf16(lo_.z); v_[3] = to_bf16(lo_.w);                     \
      v_[4] = to_bf16(hi_.x); v_[5] = to_bf16(hi_.y);                     \
      v_[6] = to_bf16(hi_.z); v_[7] = to_bf16(hi_.w);                     \
      a[ks] = v_;                                                         \
    }                                                                     \
  } while (0)

#define MFMA(bb)                                                          \
  do {                                                                    \
    _Pragma("unroll")                                                     \
    for (int nt = 0; nt < 4; ++nt) acc[nt] = (f32x4){0.f, 0.f, 0.f, 0.f}; \
    _Pragma("unroll")                                                     \
    for (int ks = 0; ks < 8; ++ks)                                        \
      _Pragma("unroll")                                                   \
      for (int nt = 0; nt < 4; ++nt) {                                    \
        bf16x8 bv_ = *(const bf16x8*)&Bl[(bb) + (ks * 4 + nt) * 512 + lane * 8]; \
        acc[nt] = __builtin_amdgcn_mfma_f32_16x16x32_bf16(a[ks], bv_, acc[nt], 0, 0, 0); \
      }                                                                   \
  } while (0)

#define STORE(t, zo)                                                      \
  do {                                                                    \
    float* ob_ = out + ((size_t)(t) * 16) * 64 + l15 + (zo);              \
    _Pragma("unroll")                                                     \
    for (int r = 0; r < 4; ++r)                                           \
      _Pragma("unroll")                                                   \
      for (int nt = 0; nt < 4; ++nt)                                      \
        __builtin_nontemporal_store(acc[nt][r], &ob_[(4 * lg + r) * 64 + nt * 16]); \
  } while (0)

  // Stage B -> LDS once (frag-set idx = ks*4+nt; this wave stages w*8+j).
#pragma unroll
  for (int j = 0; j < 8; ++j) {
    int idx = w * 8 + j;
    int ks = idx >> 2, nt = idx & 3;
    const __bf16* src = Tb2 + (nt * 16 + l15) * 256 + ks * 32 + lg * 8;
    GLD_LDS16(src, &Bl[idx * 512]);
  }
  __syncthreads();

  unsigned bb = 0;
  asm volatile("" : "+v"(bb));

#pragma unroll 1
  for (int rep = 0; rep < 2; ++rep) {
    unsigned zo = 0;
    asm volatile("" : "+v"(zo));   // opaque 0: pass 2 can't CSE pass 1's loads

    ISSUE(mt0, zo);
    CVT();
    ISSUE(mt0 + 1, zo);
    MFMA(bb);
    STORE(mt0, zo);
    CVT();
    MFMA(bb);
    STORE(mt0 + 1, zo);
  }

#undef ISSUE
#undef CVT
#undef MFMA
#undef STORE
}

// ---------------------------------------------------------------------------
extern "C" void kernel_launch(void* const* d_in, const int* in_sizes, int n_in,
                              void* d_out, int out_size, void* d_ws, size_t ws_size,
                              hipStream_t stream) {
  const float* x     = (const float*)d_in[0];
  const float* theta = (const float*)d_in[1];
  const float* phi   = (const float*)d_in[2];
  const float* outph = (const float*)d_in[3];
  float* out = (float*)d_out;

  char* ws = (char*)d_ws;
  float4* t4  = (float4*)ws;                      // 512 KB
  float2* t2  = (float2*)(ws + 512 * 1024);       // 256 KB
  __bf16* Tb2 = (__bf16*)(ws + 768 * 1024);       // 32 KB frag-ordered T

  olk_params<<<128, 256, 0, stream>>>(theta, phi, t4, t2);
  olk_build<<<16, 256, 0, stream>>>(outph, t4, t2, Tb2);
  olk_mm<<<1024, 256, 0, stream>>>(x, Tb2, out);
}